// Round 5
// baseline (608.252 us; speedup 1.0000x reference)
//
#include <hip/hip_runtime.h>
#include <hip/hip_bf16.h>

#define B_ 4
#define N_ 4096
#define C_ 64
#define R_ 16
#define EPS_ 1e-12f

typedef __attribute__((ext_vector_type(8))) short bf16x8;
typedef __attribute__((ext_vector_type(4))) float f32x4;

static __device__ __forceinline__ unsigned short f2bf(float f) {
    unsigned int u = __float_as_uint(f);
    unsigned int r = (u + 0x7fffu + ((u >> 16) & 1u)) >> 16;
    return (unsigned short)r;
}

// K0f fragment layout: [b][rowtile=row/16][k32=k/32][fq=(k/8)&3][fr=row&15][e=k&7]
// One wave's A fragment for (rowtile,k32) = contiguous 1 KiB, lane l at +l*16B.
static __device__ __forceinline__ size_t k0f_off(int b, int rt, int k32, int fq, int fr) {
    return ((((size_t)(b * 256 + rt)) * 128 + k32) * 4 + fq) * 128 + fr * 8;
}

// Pass 1 (v5, symmetric dual-orientation): block (ti<=tj) stages W(I,J) and
// W(J,I) in LDS; each thread emits row-fragments for BOTH orientations:
//   orient1 row I+ii: k0 = (W1[ii][jq+q] + W2[jq+q][ii]) * a1h[q]
//   orient2 row J+ii: k0 = (W2[ii][jq+q] + W1[jq+q][ii]) * a2h[q]
// No transpose round-trip, 2 barriers/batch, deg via quad-shfl + atomics.
__global__ __launch_bounds__(256) void k_pass1(
    const float* __restrict__ W, const float* __restrict__ U,
    unsigned short* __restrict__ K0, float* __restrict__ deg)
{
    const int tj = blockIdx.x, ti = blockIdx.y;
    if (ti > tj) return;
    const int I = ti * 64, J = tj * 64;
    const bool diag = (ti == tj);
    const int t = threadIdx.x;
    const int ii = t >> 2, g = t & 3, jq = g * 16;

    __shared__ float UI[64][17], UJ[64][17];
    __shared__ float W1[64][65];   // W1[r][c] = W[b, I+r, J+c]
    __shared__ float W2[64][65];   // W2[r][c] = W[b, J+r, I+c]

    // stage U rows for both blocks (coalesced float4)
    {
        const int row = t >> 2, q4 = t & 3;
        const float4 vj = *(const float4*)(U + (size_t)(J + row) * R_ + q4 * 4);
        UJ[row][q4*4+0] = vj.x; UJ[row][q4*4+1] = vj.y;
        UJ[row][q4*4+2] = vj.z; UJ[row][q4*4+3] = vj.w;
        const float4 vi = *(const float4*)(U + (size_t)(I + row) * R_ + q4 * 4);
        UI[row][q4*4+0] = vi.x; UI[row][q4*4+1] = vi.y;
        UI[row][q4*4+2] = vi.z; UI[row][q4*4+3] = vi.w;
    }

    // issue batch-0 W loads early (hidden under the gate compute below)
    float4 w1v[4], w2v[4];
    #pragma unroll
    for (int k = 0; k < 4; k++) {
        const int idx = t + 256 * k, row = idx >> 4, c4 = idx & 15;
        w1v[k] = *(const float4*)(W + ((size_t)(I + row)) * N_ + J + c4 * 4);
    }
    if (!diag) {
        #pragma unroll
        for (int k = 0; k < 4; k++) {
            const int idx = t + 256 * k, row = idx >> 4, c4 = idx & 15;
            w2v[k] = *(const float4*)(W + ((size_t)(J + row)) * N_ + I + c4 * 4);
        }
    }
    __syncthreads(); // UI/UJ ready

    // gate fragments (0.5 pre-folded), computed once
    float a1[16], a2[16];
    {
        float u1[16], u2[16];
        #pragma unroll
        for (int k2 = 0; k2 < 16; k2++) { u1[k2] = UI[ii][k2]; u2[k2] = UJ[ii][k2]; }
        #pragma unroll
        for (int q = 0; q < 16; q++) {
            float s = 0.f;
            #pragma unroll
            for (int k2 = 0; k2 < 16; k2++) s += u1[k2] * UJ[jq + q][k2];
            a1[q] = 0.5f / (1.0f + __expf(-s));
        }
        if (!diag) {
            #pragma unroll
            for (int q = 0; q < 16; q++) {
                float s = 0.f;
                #pragma unroll
                for (int k2 = 0; k2 < 16; k2++) s += u2[k2] * UI[jq + q][k2];
                a2[q] = 0.5f / (1.0f + __expf(-s));
            }
        }
    }

    float (*W2p)[65] = diag ? W1 : W2;

    for (int b = 0; b < B_; b++) {
        if (b) __syncthreads(); // prior consume done before overwrite
        #pragma unroll
        for (int k = 0; k < 4; k++) {
            const int idx = t + 256 * k, row = idx >> 4, c4 = idx & 15;
            *(float4*)&W1[row][c4 * 4] = w1v[k];
        }
        if (!diag) {
            #pragma unroll
            for (int k = 0; k < 4; k++) {
                const int idx = t + 256 * k, row = idx >> 4, c4 = idx & 15;
                *(float4*)&W2[row][c4 * 4] = w2v[k];
            }
        }
        __syncthreads(); // tiles staged

        if (b < B_ - 1) { // prefetch next batch (hidden under consume)
            const float* Wn = W + (size_t)(b + 1) * N_ * N_;
            #pragma unroll
            for (int k = 0; k < 4; k++) {
                const int idx = t + 256 * k, row = idx >> 4, c4 = idx & 15;
                w1v[k] = *(const float4*)(Wn + ((size_t)(I + row)) * N_ + J + c4 * 4);
            }
            if (!diag) {
                #pragma unroll
                for (int k = 0; k < 4; k++) {
                    const int idx = t + 256 * k, row = idx >> 4, c4 = idx & 15;
                    w2v[k] = *(const float4*)(Wn + ((size_t)(J + row)) * N_ + I + c4 * 4);
                }
            }
        }

        // ---- orientation 1: row I+ii, k-cols J+jq..+15 ----
        {
            float r1[16];
            #pragma unroll
            for (int m = 0; m < 4; m++)
                *(float4*)&r1[4 * m] = *(const float4*)&W1[ii][jq + 4 * m];
            float s = 0.f;
            unsigned int pk[8];
            #pragma unroll
            for (int q = 0; q < 16; q++) {
                float k0 = (r1[q] + W2p[jq + q][ii]) * a1[q];
                s += k0;
                unsigned short us = f2bf(k0);
                if (q & 1) pk[q >> 1] |= ((unsigned int)us) << 16;
                else       pk[q >> 1] = us;
            }
            unsigned short* dst = K0 + k0f_off(b, (I + ii) >> 4,
                                               (J >> 5) + (g >> 1), (g & 1) * 2, ii & 15);
            *(int4*)(dst)       = make_int4(pk[0], pk[1], pk[2], pk[3]);
            *(int4*)(dst + 128) = make_int4(pk[4], pk[5], pk[6], pk[7]);
            s += __shfl_xor(s, 1, 64);
            s += __shfl_xor(s, 2, 64);
            if (g == 0) atomicAdd(deg + b * N_ + I + ii, s);
        }
        // ---- orientation 2: row J+ii, k-cols I+jq..+15 ----
        if (!diag) {
            float r2[16];
            #pragma unroll
            for (int m = 0; m < 4; m++)
                *(float4*)&r2[4 * m] = *(const float4*)&W2[ii][jq + 4 * m];
            float s = 0.f;
            unsigned int pk[8];
            #pragma unroll
            for (int q = 0; q < 16; q++) {
                float k0 = (r2[q] + W1[jq + q][ii]) * a2[q];
                s += k0;
                unsigned short us = f2bf(k0);
                if (q & 1) pk[q >> 1] |= ((unsigned int)us) << 16;
                else       pk[q >> 1] = us;
            }
            unsigned short* dst = K0 + k0f_off(b, (J + ii) >> 4,
                                               (I >> 5) + (g >> 1), (g & 1) * 2, ii & 15);
            *(int4*)(dst)       = make_int4(pk[0], pk[1], pk[2], pk[3]);
            *(int4*)(dst + 128) = make_int4(pk[4], pk[5], pk[6], pk[7]);
            s += __shfl_xor(s, 1, 64);
            s += __shfl_xor(s, 2, 64);
            if (g == 0) atomicAdd(deg + b * N_ + J + ii, s);
        }
    }
}

// xdTf fragment layout: [b][k32=j/32][cg=c/16][fq=(j/8)&3][fr=c&15][e=j&7]
// value = bf16( x[b,j,c] * rsqrt(deg[b,j]) )
__global__ __launch_bounds__(256) void k_xdT(
    const float* __restrict__ x, const float* __restrict__ deg,
    unsigned short* __restrict__ xdT)
{
    const int jt = blockIdx.x, b = blockIdx.y;
    const int J = jt * 64, t = threadIdx.x;
    __shared__ float xt[64][69];
    #pragma unroll
    for (int k = 0; k < 4; k++) {
        int idx = t + 256 * k;
        int row = idx >> 4, f4 = idx & 15;
        float d = rsqrtf(fmaxf(deg[b * N_ + J + row], EPS_));
        float4 v = *(const float4*)(x + ((size_t)(b * N_ + J + row)) * C_ + f4 * 4);
        xt[row][f4*4+0] = v.x * d; xt[row][f4*4+1] = v.y * d;
        xt[row][f4*4+2] = v.z * d; xt[row][f4*4+3] = v.w * d;
    }
    __syncthreads();
    #pragma unroll
    for (int p = 0; p < 2; p++) {
        const int linear = p * 256 + t;
        const int k32h = linear >> 8, rem = linear & 255;
        const int cg = rem >> 6, l = rem & 63, fq = l >> 4, fr = l & 15;
        const int c = cg * 16 + fr;
        const int jb = k32h * 32 + fq * 8;
        unsigned int pk[4];
        #pragma unroll
        for (int m = 0; m < 4; m++) {
            pk[m] = (unsigned int)f2bf(xt[jb + 2*m][c]) |
                    ((unsigned int)f2bf(xt[jb + 2*m + 1][c]) << 16);
        }
        unsigned short* dst = xdT +
            (((size_t)(b * 128 + (J >> 5) + k32h)) * 4 + cg) * 512 + l * 8;
        *(int4*)dst = make_int4(pk[0], pk[1], pk[2], pk[3]);
    }
}

// Pass 2: split-K MFMA GEMM, 1 wave per (rowtile, K-quarter), no LDS/barriers.
// Pre-scaled fp32 atomicAdd into zeroed out (4 adds/element).
__global__ __launch_bounds__(64, 4) void k_gemm(
    const unsigned short* __restrict__ K0, const unsigned short* __restrict__ xdT,
    const float* __restrict__ deg, const float* __restrict__ wsc_p,
    float* __restrict__ out)
{
    const int blk = blockIdx.x, b = blockIdx.y;
    const int rt = blk >> 2, kq = blk & 3;   // rowtile 0..255, K-quarter 0..3
    const int l = threadIdx.x;

    const unsigned short* Ap = K0  + (size_t)(b * 256 + rt) * 65536
                                   + (size_t)(kq * 32) * 512 + l * 8;
    const unsigned short* Bp = xdT + (size_t)b * 262144
                                   + (size_t)(kq * 32) * 2048 + l * 8;

    f32x4 acc0 = {0.f,0.f,0.f,0.f}, acc1 = {0.f,0.f,0.f,0.f};
    f32x4 acc2 = {0.f,0.f,0.f,0.f}, acc3 = {0.f,0.f,0.f,0.f};

    #pragma unroll 4
    for (int k = 0; k < 32; k++) {
        bf16x8 av = *(const bf16x8*)(Ap + (size_t)k * 512);
        bf16x8 b0 = *(const bf16x8*)(Bp + (size_t)k * 2048);
        bf16x8 b1 = *(const bf16x8*)(Bp + (size_t)k * 2048 + 512);
        bf16x8 b2 = *(const bf16x8*)(Bp + (size_t)k * 2048 + 1024);
        bf16x8 b3 = *(const bf16x8*)(Bp + (size_t)k * 2048 + 1536);
        acc0 = __builtin_amdgcn_mfma_f32_16x16x32_bf16(av, b0, acc0, 0, 0, 0);
        acc1 = __builtin_amdgcn_mfma_f32_16x16x32_bf16(av, b1, acc1, 0, 0, 0);
        acc2 = __builtin_amdgcn_mfma_f32_16x16x32_bf16(av, b2, acc2, 0, 0, 0);
        acc3 = __builtin_amdgcn_mfma_f32_16x16x32_bf16(av, b3, acc3, 0, 0, 0);
    }

    const int fr = l & 15, fq = l >> 4;
    const float wsc = wsc_p[0];
    #pragma unroll
    for (int r = 0; r < 4; r++) {
        const int row = rt * 16 + fq * 4 + r;
        const float sc = wsc * rsqrtf(fmaxf(deg[b * N_ + row], EPS_));
        float* op = out + ((size_t)(b * N_ + row)) * C_;
        atomicAdd(op + fr,      sc * acc0[r]);
        atomicAdd(op + 16 + fr, sc * acc1[r]);
        atomicAdd(op + 32 + fr, sc * acc2[r]);
        atomicAdd(op + 48 + fr, sc * acc3[r]);
    }
}

extern "C" void kernel_launch(void* const* d_in, const int* in_sizes, int n_in,
                              void* d_out, int out_size, void* d_ws, size_t ws_size,
                              hipStream_t stream)
{
    const float* x   = (const float*)d_in[0];
    const float* W   = (const float*)d_in[1];
    const float* U   = (const float*)d_in[2];
    const float* wsc = (const float*)d_in[3];
    float* out = (float*)d_out;

    // workspace: K0f (bf16, 128 MiB) | deg (fp32, 64 KiB) | xdTf (bf16, 2 MiB)
    unsigned short* K0  = (unsigned short*)d_ws;
    float*          deg = (float*)((char*)d_ws + (size_t)B_ * N_ * N_ * 2);
    unsigned short* xdT = (unsigned short*)((char*)deg + (size_t)B_ * N_ * 4);

    hipMemsetAsync(deg, 0, (size_t)B_ * N_ * sizeof(float), stream);
    hipMemsetAsync(out, 0, (size_t)B_ * N_ * C_ * sizeof(float), stream);
    hipLaunchKernelGGL(k_pass1, dim3(64, 64), dim3(256), 0, stream, W, U, K0, deg);
    hipLaunchKernelGGL(k_xdT,  dim3(64, 4),   dim3(256), 0, stream, x, deg, xdT);
    hipLaunchKernelGGL(k_gemm, dim3(1024, 4), dim3(64),  0, stream, K0, xdT, deg, wsc, out);
}